// Round 1
// baseline (1456.981 us; speedup 1.0000x reference)
//
#include <hip/hip_runtime.h>

#define C 32          // channels
#define CG (C / 4)    // float4 groups per row = 8

// One thread handles 4 channels of one edge: 8 threads per edge.
// Reads t[src] (float4, coalesced across the 8-thread group), atomically
// accumulates into agg[dst]. On the first pass (deg != nullptr) the g==0
// thread also counts the edge into deg[dst].
__global__ void scatter_kernel(const float* __restrict__ t,
                               const int* __restrict__ src,
                               const int* __restrict__ dst,
                               float* __restrict__ agg,
                               float* __restrict__ deg,   // nullptr on 2nd pass
                               int E) {
    int tid = blockIdx.x * blockDim.x + threadIdx.x;
    int e = tid >> 3;
    int g = tid & 7;
    if (e >= E) return;
    int s = src[e];
    int d = dst[e];
    if (deg != nullptr && g == 0) {
        unsafeAtomicAdd(&deg[d], 1.0f);
    }
    float4 v = ((const float4*)(t + (size_t)s * C))[g];
    float* a = agg + (size_t)d * C + (size_t)g * 4;
    unsafeAtomicAdd(a + 0, v.x);
    unsafeAtomicAdd(a + 1, v.y);
    unsafeAtomicAdd(a + 2, v.z);
    unsafeAtomicAdd(a + 3, v.w);
}

// t1 = deg[row] * x - agg   (elementwise over N*C, float4-vectorized)
__global__ void combine1_kernel(const float* __restrict__ x,
                                const float* __restrict__ agg,
                                const float* __restrict__ deg,
                                float* __restrict__ t1,
                                int nc4) {
    int i = blockIdx.x * blockDim.x + threadIdx.x;
    if (i >= nc4) return;
    float dg = deg[i >> 3];  // i / CG
    float4 xv = ((const float4*)x)[i];
    float4 av = ((const float4*)agg)[i];
    float4 r;
    r.x = dg * xv.x - av.x;
    r.y = dg * xv.y - av.y;
    r.z = dg * xv.z - av.z;
    r.w = dg * xv.w - av.w;
    ((float4*)t1)[i] = r;
}

// y = w0*x + w1*t1 + w2*(deg*t1 - agg2)
__global__ void final_kernel(const float* __restrict__ x,
                             const float* __restrict__ t1,
                             const float* __restrict__ agg,
                             const float* __restrict__ deg,
                             const float* __restrict__ w,
                             float* __restrict__ y,
                             int nc4) {
    int i = blockIdx.x * blockDim.x + threadIdx.x;
    if (i >= nc4) return;
    float w0 = w[0], w1 = w[1], w2 = w[2];
    float dg = deg[i >> 3];
    float4 xv = ((const float4*)x)[i];
    float4 tv = ((const float4*)t1)[i];
    float4 av = ((const float4*)agg)[i];
    float4 r;
    r.x = w0 * xv.x + w1 * tv.x + w2 * (dg * tv.x - av.x);
    r.y = w0 * xv.y + w1 * tv.y + w2 * (dg * tv.y - av.y);
    r.z = w0 * xv.z + w1 * tv.z + w2 * (dg * tv.z - av.z);
    r.w = w0 * xv.w + w1 * tv.w + w2 * (dg * tv.w - av.w);
    ((float4*)y)[i] = r;
}

extern "C" void kernel_launch(void* const* d_in, const int* in_sizes, int n_in,
                              void* d_out, int out_size, void* d_ws, size_t ws_size,
                              hipStream_t stream) {
    const float* x    = (const float*)d_in[0];
    const float* w    = (const float*)d_in[1];
    const int*   esrc = (const int*)d_in[2];
    const int*   edst = (const int*)d_in[3];
    float*       y    = (float*)d_out;

    const int N = in_sizes[0] / C;     // 100000
    const int E = in_sizes[2];         // 1600000
    const int nc  = N * C;
    const int nc4 = nc / 4;

    // workspace layout: deg[N] | t1[N*C] | agg[N*C]  (~26 MB)
    float* ws  = (float*)d_ws;
    size_t off = ((size_t)N + 63) & ~(size_t)63;   // 256B-align t1
    float* deg = ws;
    float* t1  = ws + off;
    float* agg = t1 + (size_t)nc;

    hipMemsetAsync(deg, 0, (size_t)N * sizeof(float), stream);
    hipMemsetAsync(agg, 0, (size_t)nc * sizeof(float), stream);

    const int sthreads = E * 8;
    const int sblocks  = (sthreads + 255) / 256;
    const int cblocks  = (nc4 + 255) / 256;

    // pass 1: agg = A @ x (scatter), deg counted alongside
    scatter_kernel<<<sblocks, 256, 0, stream>>>(x, esrc, edst, agg, deg, E);
    // t1 = deg*x - agg  (= L @ x)
    combine1_kernel<<<cblocks, 256, 0, stream>>>(x, agg, deg, t1, nc4);

    // pass 2: agg = A @ t1
    hipMemsetAsync(agg, 0, (size_t)nc * sizeof(float), stream);
    scatter_kernel<<<sblocks, 256, 0, stream>>>(t1, esrc, edst, agg, nullptr, E);

    // y = w0*x + w1*t1 + w2*(deg*t1 - agg)
    final_kernel<<<cblocks, 256, 0, stream>>>(x, t1, agg, deg, w, y, nc4);
}

// Round 2
// 426.583 us; speedup vs baseline: 3.4155x; 3.4155x over previous
//
#include <hip/hip_runtime.h>

#define C 32
#define NT 256
#define SCAN_CHUNK 1024   // elements per block in scan1/scan3 (256 thr x 4)

// ---- CSR build: histogram of in-degrees ----
__global__ void hist_kernel(const int* __restrict__ dst, int* __restrict__ ideg, int E) {
    int e = blockIdx.x * blockDim.x + threadIdx.x;
    if (e < E) atomicAdd(&ideg[dst[e]], 1);
}

// ---- exclusive scan, 3-kernel: per-block scan, scan of block sums, add offsets ----
__global__ void scan1_kernel(const int* __restrict__ ideg, int* __restrict__ row_start,
                             int* __restrict__ bsums, int N) {
    __shared__ int sdata[NT];
    int t = threadIdx.x;
    int base = blockIdx.x * SCAN_CHUNK + t * 4;
    int v0 = 0, v1 = 0, v2 = 0, v3 = 0;
    if (base + 3 < N) {
        int4 q = *(const int4*)(ideg + base);
        v0 = q.x; v1 = q.y; v2 = q.z; v3 = q.w;
    } else {
        if (base + 0 < N) v0 = ideg[base + 0];
        if (base + 1 < N) v1 = ideg[base + 1];
        if (base + 2 < N) v2 = ideg[base + 2];
        if (base + 3 < N) v3 = ideg[base + 3];
    }
    int mysum = v0 + v1 + v2 + v3;
    sdata[t] = mysum;
    __syncthreads();
    for (int off = 1; off < NT; off <<= 1) {
        int v = (t >= off) ? sdata[t - off] : 0;
        __syncthreads();
        sdata[t] += v;
        __syncthreads();
    }
    int ex = sdata[t] - mysum;            // exclusive prefix within block
    if (t == NT - 1) bsums[blockIdx.x] = sdata[t];
    if (base + 3 < N) {
        int4 r;
        r.x = ex; r.y = ex + v0; r.z = ex + v0 + v1; r.w = ex + v0 + v1 + v2;
        *(int4*)(row_start + base) = r;
    } else {
        int r = ex;
        if (base + 0 < N) { row_start[base + 0] = r; r += v0; }
        if (base + 1 < N) { row_start[base + 1] = r; r += v1; }
        if (base + 2 < N) { row_start[base + 2] = r; r += v2; }
        if (base + 3 < N) { row_start[base + 3] = r; }
    }
}

__global__ void scan2_kernel(int* __restrict__ bsums, int NB) {
    // NB must be <= NT (it is: ceil(100000/1024) = 98)
    __shared__ int sdata[NT];
    int t = threadIdx.x;
    int v = (t < NB) ? bsums[t] : 0;
    sdata[t] = v;
    __syncthreads();
    for (int off = 1; off < NT; off <<= 1) {
        int u = (t >= off) ? sdata[t - off] : 0;
        __syncthreads();
        sdata[t] += u;
        __syncthreads();
    }
    if (t < NB) bsums[t] = sdata[t] - v;  // exclusive
}

__global__ void scan3_kernel(int* __restrict__ row_start, int* __restrict__ cursor,
                             const int* __restrict__ bsums, int N, int E) {
    int base = blockIdx.x * SCAN_CHUNK + threadIdx.x * 4;
    int off = bsums[blockIdx.x];
    if (blockIdx.x == 0 && threadIdx.x == 0) row_start[N] = E;
    if (base + 3 < N) {
        int4 q = *(const int4*)(row_start + base);
        q.x += off; q.y += off; q.z += off; q.w += off;
        *(int4*)(row_start + base) = q;
        *(int4*)(cursor + base) = q;
    } else {
        for (int k = 0; k < 4; ++k) {
            int i = base + k;
            if (i < N) {
                int v = row_start[i] + off;
                row_start[i] = v;
                cursor[i] = v;
            }
        }
    }
}

// ---- CSR fill: csr_src grouped by dst (order within a row is irrelevant) ----
__global__ void fill_kernel(const int* __restrict__ src, const int* __restrict__ dst,
                            int* __restrict__ cursor, int* __restrict__ csr, int E) {
    int e = blockIdx.x * blockDim.x + threadIdx.x;
    if (e >= E) return;
    int pos = atomicAdd(&cursor[dst[e]], 1);
    csr[pos] = src[e];
}

// ---- gather matvec 1: t1 = deg*x - A@x (one wave per node, 2 edges/iter) ----
__global__ void gather1_kernel(const float* __restrict__ x,
                               const int* __restrict__ csr,
                               const int* __restrict__ row_start,
                               float* __restrict__ t1, int N) {
    int w = (blockIdx.x * blockDim.x + threadIdx.x) >> 6;  // wave id = node
    if (w >= N) return;
    int lane = threadIdx.x & 63;
    int half = lane >> 5;
    int ch = lane & 31;
    int rs = row_start[w];
    int re = row_start[w + 1];
    float acc = 0.f;
    for (int j = rs + half; j < re; j += 2)
        acc += x[(size_t)csr[j] * C + ch];
    acc += __shfl_xor(acc, 32, 64);       // combine the two half-waves
    if (half == 0) {
        float dg = (float)(re - rs);
        size_t o = (size_t)w * C + ch;
        t1[o] = dg * x[o] - acc;
    }
}

// ---- gather matvec 2 fused with final combine:
//      y = w0*x + w1*t1 + w2*(deg*t1 - A@t1) ----
__global__ void gather2_kernel(const float* __restrict__ x,
                               const float* __restrict__ t1,
                               const int* __restrict__ csr,
                               const int* __restrict__ row_start,
                               const float* __restrict__ wts,
                               float* __restrict__ y, int N) {
    int w = (blockIdx.x * blockDim.x + threadIdx.x) >> 6;
    if (w >= N) return;
    int lane = threadIdx.x & 63;
    int half = lane >> 5;
    int ch = lane & 31;
    int rs = row_start[w];
    int re = row_start[w + 1];
    float acc = 0.f;
    for (int j = rs + half; j < re; j += 2)
        acc += t1[(size_t)csr[j] * C + ch];
    acc += __shfl_xor(acc, 32, 64);
    if (half == 0) {
        float dg = (float)(re - rs);
        size_t o = (size_t)w * C + ch;
        float tv = t1[o];
        y[o] = wts[0] * x[o] + wts[1] * tv + wts[2] * (dg * tv - acc);
    }
}

extern "C" void kernel_launch(void* const* d_in, const int* in_sizes, int n_in,
                              void* d_out, int out_size, void* d_ws, size_t ws_size,
                              hipStream_t stream) {
    const float* x    = (const float*)d_in[0];
    const float* wts  = (const float*)d_in[1];
    const int*   esrc = (const int*)d_in[2];
    const int*   edst = (const int*)d_in[3];
    float*       y    = (float*)d_out;

    const int N = in_sizes[0] / C;     // 100000
    const int E = in_sizes[2];         // 1600000

    // workspace: ideg[N] | row_start[N+1] | cursor[N] | bsums[256] | csr[E] | t1[N*C]
    char* p = (char*)d_ws;
    auto align16 = [](size_t s) { return (s + 15) & ~(size_t)15; };
    int* ideg      = (int*)p; p += align16((size_t)N * 4);
    int* row_start = (int*)p; p += align16((size_t)(N + 1) * 4);
    int* cursor    = (int*)p; p += align16((size_t)N * 4);
    int* bsums     = (int*)p; p += align16((size_t)NT * 4);
    int* csr       = (int*)p; p += align16((size_t)E * 4);
    float* t1      = (float*)p;

    const int NB = (N + SCAN_CHUNK - 1) / SCAN_CHUNK;   // 98 <= 256

    hipMemsetAsync(ideg, 0, (size_t)N * 4, stream);

    const int eblocks = (E + NT - 1) / NT;
    hist_kernel <<<eblocks, NT, 0, stream>>>(edst, ideg, E);
    scan1_kernel<<<NB, NT, 0, stream>>>(ideg, row_start, bsums, N);
    scan2_kernel<<<1, NT, 0, stream>>>(bsums, NB);
    scan3_kernel<<<NB, NT, 0, stream>>>(row_start, cursor, bsums, N, E);
    fill_kernel <<<eblocks, NT, 0, stream>>>(esrc, edst, cursor, csr, E);

    const int gblocks = ((size_t)N * 64 + NT - 1) / NT;  // one wave per node
    gather1_kernel<<<gblocks, NT, 0, stream>>>(x, csr, row_start, t1, N);
    gather2_kernel<<<gblocks, NT, 0, stream>>>(x, t1, csr, row_start, wts, y, N);
}